// Round 4
// baseline (197.879 us; speedup 1.0000x reference)
//
#include <hip/hip_runtime.h>
#include <hip/hip_bf16.h>
#include <stdint.h>

// Fastfood 2D conv, MI355X. fp32 I/O:
// input (16,256,32,32), B/G/S (1,4096), bias (512), P (4096) i32 -> out (16,512,32,32).
// Per pixel: patch j=kk*256+ch (2304, pad 4096), *B, FWHT4096, perm P, *G, FWHT4096,
// *S[0:512]+bias.
//
// R4: block=(b,oh), pixel pairs (2q,2q+1) packed bf16x2. FWHT4096 = 3x radix-16
// rounds, 2 LDS exchanges/pass through TWO alternating 4096-word buffers with the
// verified conflict-free XOR swizzle -> ONE barrier per exchange (5/iter, was 12).
// All LDS addresses precomputed in VGPRs; buffer select is a compile-time byte
// offset (parity-expanded loop body). Patches read straight from global (L2-hot).
// Outputs accumulate in a 16 KB LDS buffer (bf16x2, swizzled conflict-free);
// single flush writes full 128B channel rows -> no transpose kernel, no ws.
// LDS = 2*16KB exchange + 16KB out = 65536 B exactly -> 2 blocks/CU.

__device__ __forceinline__ int swz(int j) {
    return j ^ ((j >> 5) & 7) ^ (((j >> 8) & 1) * 24) ^ (((j >> 9) & 1) * 8);
}
__device__ __forceinline__ uint32_t pk2(float a, float b) {
    __hip_bfloat162 h = __float22bfloat162_rn(make_float2(a, b));
    union { __hip_bfloat162 h; uint32_t u; } c; c.h = h; return c.u;
}
__device__ __forceinline__ float2 unpk(uint32_t u) {
    return make_float2(__uint_as_float(u << 16), __uint_as_float(u & 0xFFFF0000u));
}
__device__ __forceinline__ void h16p(float2* x) {
    #pragma unroll
    for (int h = 1; h < 16; h <<= 1) {
        #pragma unroll
        for (int g = 0; g < 16; g += 2 * h) {
            #pragma unroll
            for (int u = g; u < g + h; ++u) {
                float2 a = x[u], b = x[u + h];
                x[u]     = make_float2(a.x + b.x, a.y + b.y);  // v_pk_add_f32
                x[u + h] = make_float2(a.x - b.x, a.y - b.y);
            }
        }
    }
}

#define STW(abyte, off, w) \
    (*reinterpret_cast<uint32_t*>(reinterpret_cast<char*>(lds) + (abyte) + (off)) = (w))
#define LDW(abyte, off) \
    (*reinterpret_cast<const uint32_t*>(reinterpret_cast<const char*>(lds) + (abyte) + (off)))

// One pixel pair, PAR in {0,1}: exchange buffers alternate as byte offsets
// OA=PAR*16384, OB=(1-PAR)*16384 -> all buffer selects are immediates.
#define PROC(PAR)                                                                  \
{                                                                                  \
    const int q = 2 * m + (PAR);                                                   \
    constexpr int OA = (PAR) * 16384, OB = (1 - (PAR)) * 16384;                    \
    float2 x[16];                                                                  \
    _Pragma("unroll")                                                              \
    for (int kh = 0; kh < 3; ++kh) {                                               \
        float lm = 0.f, l0 = 0.f, l1 = 0.f, lp = 0.f;                              \
        if (ok[kh]) {                                                              \
            const float* p = rp[kh] + 2 * q;                                       \
            float2 c2 = *reinterpret_cast<const float2*>(p);                       \
            l0 = c2.x; l1 = c2.y;                                                  \
            if (q > 0)  lm = p[-1];                                                \
            if (q < 15) lp = p[2];                                                 \
        }                                                                          \
        x[kh * 3 + 0] = make_float2(lm * Bv[kh * 3 + 0], l0 * Bv[kh * 3 + 0]);     \
        x[kh * 3 + 1] = make_float2(l0 * Bv[kh * 3 + 1], l1 * Bv[kh * 3 + 1]);     \
        x[kh * 3 + 2] = make_float2(l1 * Bv[kh * 3 + 2], lp * Bv[kh * 3 + 2]);     \
    }                                                                              \
    _Pragma("unroll")                                                              \
    for (int r = 9; r < 16; ++r) x[r] = make_float2(0.f, 0.f);                     \
    h16p(x);                                          /* pass0 round A */          \
    _Pragma("unroll")                                                              \
    for (int r = 0; r < 16; ++r) STW(aA[r], OA, pk2(x[r].x, x[r].y));              \
    __syncthreads();                                                               \
    _Pragma("unroll")                                                              \
    for (int r = 0; r < 16; ++r) x[r] = unpk(LDW(aB[r], OA));                      \
    h16p(x);                                          /* round B */                \
    _Pragma("unroll")                                                              \
    for (int r = 0; r < 16; ++r) STW(aB[r], OB, pk2(x[r].x, x[r].y));              \
    __syncthreads();                                                               \
    _Pragma("unroll")                                                              \
    for (int r = 0; r < 16; ++r) x[r] = unpk(LDW(aC[r], OB));                      \
    h16p(x);                                          /* round C */                \
    _Pragma("unroll")                                                              \
    for (int r = 0; r < 16; ++r) STW(aC[r], OA, pk2(x[r].x, x[r].y));              \
    __syncthreads();                                                               \
    _Pragma("unroll")                                                              \
    for (int r = 0; r < 16; ++r) {                    /* perm + G -> A layout */    \
        float2 v = unpk(LDW(PA[r], OA));                                           \
        x[r] = make_float2(Gv[r] * v.x, Gv[r] * v.y);                              \
    }                                                                              \
    h16p(x);                                          /* pass1 round A */          \
    _Pragma("unroll")                                                              \
    for (int r = 0; r < 16; ++r) STW(aA[r], OB, pk2(x[r].x, x[r].y));              \
    __syncthreads();                                                               \
    _Pragma("unroll")                                                              \
    for (int r = 0; r < 16; ++r) x[r] = unpk(LDW(aB[r], OB));                      \
    h16p(x);                                          /* round B */                \
    _Pragma("unroll")                                                              \
    for (int r = 0; r < 16; ++r) STW(aB[r], OA, pk2(x[r].x, x[r].y));              \
    __syncthreads();                                                               \
    _Pragma("unroll")                                                              \
    for (int r = 0; r < 16; ++r) x[r] = unpk(LDW(aC[r], OA));                      \
    h16p(x);                                          /* round C: j = 16t + r */   \
    if (t < 32) {                                     /* S*x+bias -> out accum */  \
        const int qb = 8192 + 512 * q;                                             \
        _Pragma("unroll")                                                          \
        for (int r = 0; r < 16; ++r)                                               \
            lds[qb + epiW[r]] =                                                    \
                pk2(Sv[r] * x[r].x + Cv[r], Sv[r] * x[r].y + Cv[r]);               \
    }                                                                              \
}

__global__ __launch_bounds__(256, 2)
void fastfood_kernel(const float* __restrict__ in,
                     const float* __restrict__ Bm,
                     const float* __restrict__ Gm,
                     const float* __restrict__ Sm,
                     const float* __restrict__ bias,
                     const int* __restrict__ P,
                     float* __restrict__ out)
{
    // [0,4096): exchange buf0 | [4096,8192): buf1 | [8192,16384): out accum (bf16x2)
    __shared__ uint32_t lds[16384];

    const int t  = threadIdx.x;
    const int t1 = t >> 4, t0 = t & 15;
    const int b  = blockIdx.x >> 5;
    const int oh = blockIdx.x & 31;

    // ---- precomputed LDS byte addresses (loop-invariant, live in VGPRs)
    int aA[16], aB[16], aC[16], PA[16];
    float Gv[16];
    #pragma unroll
    for (int r = 0; r < 16; ++r) {
        aA[r] = swz(256 * r + t) * 4;                 // round-A layout j = 256r + t
        aB[r] = swz(256 * t1 + 16 * r + t0) * 4;      // round-B layout
        aC[r] = swz(256 * t1 + 16 * t0 + r) * 4;      // round-C layout j = 16t + r
        PA[r] = swz(P[r * 256 + t]) * 4;              // permutation gather
        Gv[r] = Gm[r * 256 + t];
    }
    float Bv[9];
    #pragma unroll
    for (int r = 0; r < 9; ++r) Bv[r] = Bm[r * 256 + t];
    float Sv[16], Cv[16];
    if (t < 32) {
        #pragma unroll
        for (int r = 0; r < 16; ++r) { Sv[r] = Sm[16 * t + r]; Cv[r] = bias[16 * t + r]; }
    }
    // out-accum column for oc = 16t + r: word 16t + (r ^ ((t>>1)&7))  (1 lane/bank)
    int epiW[16];
    #pragma unroll
    for (int r = 0; r < 16; ++r) epiW[r] = 16 * t + (r ^ ((t >> 1) & 7));

    // ---- patch row pointers, channel = t (L2-resident reads)
    const float* rowbase = in + (size_t)(b * 256 + t) * 1024;
    const float* rp[3]; bool ok[3];
    #pragma unroll
    for (int kh = 0; kh < 3; ++kh) {
        const int ih = oh - 1 + kh;
        ok[kh] = (unsigned)ih < 32u;
        rp[kh] = rowbase + ih * 32;
    }

    #pragma unroll 1
    for (int m = 0; m < 8; ++m) {
        PROC(0)
        PROC(1)
    }

    // ---- flush: thread t -> channels 2t, 2t+1; full 128 B rows, fully coalesced lines
    __syncthreads();
    {
        const int oc0 = 2 * t, oc1 = 2 * t + 1;
        const int c0 = (oc0 & ~15) | ((oc0 & 15) ^ ((oc0 >> 5) & 7));
        const int c1 = (oc1 & ~15) | ((oc1 & 15) ^ ((oc1 >> 5) & 7));
        float r0[32], r1[32];
        #pragma unroll
        for (int qq = 0; qq < 16; ++qq) {
            float2 va = unpk(lds[8192 + 512 * qq + c0]);
            float2 vb = unpk(lds[8192 + 512 * qq + c1]);
            r0[2 * qq] = va.x; r0[2 * qq + 1] = va.y;
            r1[2 * qq] = vb.x; r1[2 * qq + 1] = vb.y;
        }
        float* o0 = out + ((size_t)(b * 512 + oc0) * 1024 + oh * 32);
        float* o1 = o0 + 1024;
        #pragma unroll
        for (int g = 0; g < 8; ++g) {
            *reinterpret_cast<float4*>(o0 + 4 * g) =
                make_float4(r0[4 * g], r0[4 * g + 1], r0[4 * g + 2], r0[4 * g + 3]);
            *reinterpret_cast<float4*>(o1 + 4 * g) =
                make_float4(r1[4 * g], r1[4 * g + 1], r1[4 * g + 2], r1[4 * g + 3]);
        }
    }
}

extern "C" void kernel_launch(void* const* d_in, const int* in_sizes, int n_in,
                              void* d_out, int out_size, void* d_ws, size_t ws_size,
                              hipStream_t stream) {
    const float* in   = (const float*)d_in[0];
    const float* Bm   = (const float*)d_in[1];
    const float* Gm   = (const float*)d_in[2];
    const float* Sm   = (const float*)d_in[3];
    const float* bias = (const float*)d_in[4];
    const int*   P    = (const int*)d_in[5];
    float* out = (float*)d_out;

    dim3 grid(16 * 32), block(256);
    fastfood_kernel<<<grid, block, 0, stream>>>(in, Bm, Gm, Sm, bias, P, out);
}